// Round 12
// baseline (213.784 us; speedup 1.0000x reference)
//
#include <hip/hip_runtime.h>

typedef __attribute__((ext_vector_type(8))) short short8;
typedef __attribute__((ext_vector_type(4))) short s4v;
typedef __attribute__((ext_vector_type(2))) uint uint2v;
typedef __attribute__((ext_vector_type(4))) uint uint4v;
typedef __attribute__((ext_vector_type(4))) float floatx4;

#define CCH   256
#define QSCALE 0.17677669529663687f  // 32^-0.5
#define LOG2E  1.4426950408889634f

__device__ __forceinline__ unsigned short f2bf(float f) {
    unsigned u = __float_as_uint(f);
    u = u + 0x7fffu + ((u >> 16) & 1u);
    return (unsigned short)(u >> 16);
}

// pack two fp32 -> bf16x2 with round-half-up: (u+0x8000)>>16, fused via v_perm
__device__ __forceinline__ uint pk2bf(float a, float b) {
    uint ua = __float_as_uint(a) + 0x8000u;
    uint ub = __float_as_uint(b) + 0x8000u;
    return __builtin_amdgcn_perm(ub, ua, 0x07060302u);
}

__device__ __forceinline__ void gl_lds16(const void* g, void* l) {
    __builtin_amdgcn_global_load_lds((const __attribute__((address_space(1))) void*)g,
                                     (__attribute__((address_space(3))) void*)l, 16, 0, 0);
}

// token (w*512+n) -> flat spatial offset (*CCH) in x/out with +4 cyclic shift
__device__ __forceinline__ int spatial_off(int token) {
    int w = token >> 9, n = token & 511;
    int wh = w >> 4, ww = (w >> 2) & 3, wd = w & 3;
    int h1 = n >> 6, w1 = (n >> 3) & 7, d1 = n & 7;
    int gh = (wh * 8 + h1 + 4) & 31;
    int gw = (ww * 8 + w1 + 4) & 31;
    int gd = (wd * 8 + d1 + 4) & 31;
    return ((gh * 32 + gw) * 32 + gd) * CCH;
}

// ---------------- fused preprocessing: xconv | wconv | pair_prep ----------------
__global__ __launch_bounds__(256) void prep(const float* __restrict__ x,
                                            const float* __restrict__ Wq,
                                            const float* __restrict__ Wp,
                                            const float* __restrict__ rpb,
                                            ushort* __restrict__ Xw,
                                            ushort* __restrict__ Wqb,
                                            ushort* __restrict__ Wpb,
                                            uint* __restrict__ Up) {
    int b = blockIdx.x;
    if (b < 4096) {
        int tid = b * 256 + threadIdx.x;   // 1048576
        int token = tid >> 5, c8 = (tid & 31) * 8;
        const float* src = x + spatial_off(token) + c8;
        float4 a = *(const float4*)src;
        float4 bb = *(const float4*)(src + 4);
        uint2v lo, hi;
        lo[0] = pk2bf(a.x, a.y);
        lo[1] = pk2bf(a.z, a.w);
        hi[0] = pk2bf(bb.x, bb.y);
        hi[1] = pk2bf(bb.z, bb.w);
        uint2v* dst = (uint2v*)(Xw + (size_t)token * 256 + c8);
        dst[0] = lo;
        dst[1] = hi;
    } else if (b < 5120) {
        int tid = (b - 4096) * 256 + threadIdx.x;   // 262144
        if (tid < 196608) {
            float s = (tid < 65536) ? (QSCALE * LOG2E) : 1.0f;
            Wqb[tid] = f2bf(Wq[tid] * s);
        } else {
            int i = tid - 196608;
            Wpb[i] = f2bf(Wp[i]);
        }
    } else {
        int tid = (b - 5120) * 256 + threadIdx.x;   // 27000
        if (tid >= 27000) return;
        int head = tid / 3375, idx = tid - head * 3375;
        uint lo = f2bf(rpb[idx * 8 + head] * LOG2E);
        uint hi = f2bf(rpb[(idx > 0 ? idx - 1 : 0) * 8 + head] * LOG2E);
        Up[tid] = lo | (hi << 16);
    }
}

// ---------------- MFMA GEMM: C[32768 x 768] = Xw @ Wqb^T -> Q/K/Vf ----------------
// V in K=16 A-fragment order; K in K=32 QK A-fragment order; Q row-major.
// Q/K epilogue: LDS-bounce transpose -> coalesced 16B packed stores.
__global__ __launch_bounds__(256) void gemm_qkv(
    const ushort* __restrict__ A,   // [32768][256] bf16
    const ushort* __restrict__ Bw,  // [768][256] bf16
    const float* __restrict__ bq,
    ushort* __restrict__ Q, ushort* __restrict__ K, ushort* __restrict__ Vf) {
    __shared__ short Sh[17408];     // main loop: As=Sh[0:8192], Bs=Sh[8192:16384]
                                    // epilogue:  128x136 bf16 tile (rows 16B-aligned)
    short* As = Sh;
    short* Bs = Sh + 8192;
    const int t = threadIdx.x;
    const int wv = t >> 6, lane = t & 63, quad = lane >> 4, col = lane & 15;
    const int m0 = blockIdx.y * 128, n0 = blockIdx.x * 128;
    const int wm = (wv & 1) * 64, wn = (wv >> 1) * 64;

    floatx4 zf = {0.f, 0.f, 0.f, 0.f};
    floatx4 acc[4][4];
#pragma unroll
    for (int i = 0; i < 4; ++i)
#pragma unroll
        for (int j = 0; j < 4; ++j) acc[i][j] = zf;

    for (int kk = 0; kk < 256; kk += 64) {
        __syncthreads();
#pragma unroll
        for (int i = 0; i < 4; ++i) {
            int s = i * 256 + t;
            int row = s >> 3, qs = s & 7;
            int qg = qs ^ (row & 7);
            gl_lds16(A + (size_t)(m0 + row) * 256 + kk + qg * 8,
                     As + (i * 256 + wv * 64) * 8);
        }
#pragma unroll
        for (int i = 0; i < 4; ++i) {
            int s = i * 256 + t;
            int row = s >> 3, qs = s & 7;
            int qg = qs ^ (row & 7);
            gl_lds16(Bw + (size_t)(n0 + row) * 256 + kk + qg * 8,
                     Bs + (i * 256 + wv * 64) * 8);
        }
        __syncthreads();
#pragma unroll
        for (int h = 0; h < 2; ++h) {
            short8 af[4], bf[4];
#pragma unroll
            for (int mi = 0; mi < 4; ++mi) {
                int row = wm + mi * 16 + col;
                af[mi] = *(const short8*)(As + (row * 8 + ((h * 4 + quad) ^ (row & 7))) * 8);
            }
#pragma unroll
            for (int ni = 0; ni < 4; ++ni) {
                int row = wn + ni * 16 + col;
                bf[ni] = *(const short8*)(Bs + (row * 8 + ((h * 4 + quad) ^ (row & 7))) * 8);
            }
#pragma unroll
            for (int mi = 0; mi < 4; ++mi)
#pragma unroll
                for (int ni = 0; ni < 4; ++ni)
                    acc[mi][ni] = __builtin_amdgcn_mfma_f32_16x16x32_bf16(af[mi], bf[ni], acc[mi][ni], 0, 0, 0);
        }
    }

    const int bx = blockIdx.x;   // 0,1: Q   2,3: K   4,5: V  (block-uniform)
    if (bx >= 4) {
        // ---- V: direct packed stores (fragment order already n-contiguous) ----
#pragma unroll
        for (int ni = 0; ni < 4; ++ni) {
            int j = n0 + wn + ni * 16 + col;
            int head = (j >> 5) & 7, hd = j & 31;
            float bias = bq[j];
            int h = hd >> 4, colv = hd & 15;
#pragma unroll
            for (int mi = 0; mi < 4; ++mi) {
                int mb = m0 + wm + mi * 16 + quad * 4;   // n&3 = r, contiguous
                int w = mb >> 9, n = mb & 511;
                size_t off = ((size_t)((w * 8 + head) * 64 + (n >> 4) * 2 + h) << 8)
                           + ((((n >> 2) & 3) * 16 + colv) << 2);
                uint2v pv;
                pv[0] = pk2bf(acc[mi][ni][0] + bias, acc[mi][ni][1] + bias);
                pv[1] = pk2bf(acc[mi][ni][2] + bias, acc[mi][ni][3] + bias);
                *(uint2v*)(Vf + off) = pv;
            }
        }
    } else {
        // ---- Q/K: LDS-bounce -> 8 coalesced 16B stores/thread ----
        __syncthreads();   // all waves done reading As/Bs
#pragma unroll
        for (int ni = 0; ni < 4; ++ni) {
            int j = n0 + wn + ni * 16 + col;
            int jloc = wn + ni * 16 + col;
            float bias = bq[j] * ((j < 256) ? (QSCALE * LOG2E) : 1.0f);
#pragma unroll
            for (int mi = 0; mi < 4; ++mi) {
                int rowb = wm + mi * 16 + quad * 4;
#pragma unroll
                for (int r = 0; r < 4; ++r)
                    Sh[(rowb + r) * 136 + jloc] = (short)f2bf(acc[mi][ni][r] + bias);
            }
        }
        __syncthreads();
        ushort* dst = (bx < 2) ? Q : K;
#pragma unroll
        for (int k8 = 0; k8 < 8; ++k8) {
            int chunk = k8 * 256 + t;        // 0..2047
            int row = chunk >> 4;            // 0..127
            int jl = (chunk & 15) * 8;       // 0..120
            int j = n0 + jl;
            int m = m0 + row;
            int w = m >> 9, n = m & 511;
            int head = (j >> 5) & 7, hd = j & 31;
            uint4v vv = *(const uint4v*)(Sh + row * 136 + jl);
            size_t off;
            if (bx < 2) {
                off = ((size_t)(w * 8 + head) * 512 + n) * 32 + hd;          // row-major
            } else {
                off = ((size_t)(w * 8 + head) << 14) + ((size_t)(n >> 4) << 9)
                    + (((hd >> 3) * 16 + (n & 15)) << 3);                    // frag order
            }
            *(uint4v*)(dst + off) = vv;
        }
    }
}

// ---------------- MFMA GEMM: out = Y @ Wpb^T + bp, scatter w/ reverse shift ----------
// Epilogue: LDS-bounce (2 half-tiles of 64 rows, 64x132 f32) -> coalesced dwordx4.
__global__ __launch_bounds__(256) void gemm_proj(
    const ushort* __restrict__ A,   // Y [32768][256] bf16
    const ushort* __restrict__ Bw,  // [256][256] bf16
    const float* __restrict__ bp,
    float* __restrict__ out) {
    __shared__ short As[128 * 64];
    __shared__ short Bs[128 * 64];
    __shared__ float Shf[64 * 132];  // 33KB bounce buffer (separate; total 65KB, 2/CU)
    const int t = threadIdx.x;
    const int wv = t >> 6, lane = t & 63, quad = lane >> 4, col = lane & 15;
    const int m0 = blockIdx.y * 128, n0 = blockIdx.x * 128;
    const int wm = (wv & 1) * 64, wn = (wv >> 1) * 64;

    floatx4 zf = {0.f, 0.f, 0.f, 0.f};
    floatx4 acc[4][4];
#pragma unroll
    for (int i = 0; i < 4; ++i)
#pragma unroll
        for (int j = 0; j < 4; ++j) acc[i][j] = zf;

    for (int kk = 0; kk < 256; kk += 64) {
        __syncthreads();
#pragma unroll
        for (int i = 0; i < 4; ++i) {
            int s = i * 256 + t;
            int row = s >> 3, qs = s & 7;
            int qg = qs ^ (row & 7);
            gl_lds16(A + (size_t)(m0 + row) * 256 + kk + qg * 8,
                     As + (i * 256 + wv * 64) * 8);
        }
#pragma unroll
        for (int i = 0; i < 4; ++i) {
            int s = i * 256 + t;
            int row = s >> 3, qs = s & 7;
            int qg = qs ^ (row & 7);
            gl_lds16(Bw + (size_t)(n0 + row) * 256 + kk + qg * 8,
                     Bs + (i * 256 + wv * 64) * 8);
        }
        __syncthreads();
#pragma unroll
        for (int h = 0; h < 2; ++h) {
            short8 af[4], bf[4];
#pragma unroll
            for (int mi = 0; mi < 4; ++mi) {
                int row = wm + mi * 16 + col;
                af[mi] = *(const short8*)(As + (row * 8 + ((h * 4 + quad) ^ (row & 7))) * 8);
            }
#pragma unroll
            for (int ni = 0; ni < 4; ++ni) {
                int row = wn + ni * 16 + col;
                bf[ni] = *(const short8*)(Bs + (row * 8 + ((h * 4 + quad) ^ (row & 7))) * 8);
            }
#pragma unroll
            for (int mi = 0; mi < 4; ++mi)
#pragma unroll
                for (int ni = 0; ni < 4; ++ni)
                    acc[mi][ni] = __builtin_amdgcn_mfma_f32_16x16x32_bf16(af[mi], bf[ni], acc[mi][ni], 0, 0, 0);
        }
    }

    // ---- epilogue: bounce 2 half-tiles (64 rows x 128 f32) through Shf ----
    float biasv[4];
#pragma unroll
    for (int ni = 0; ni < 4; ++ni) biasv[ni] = bp[n0 + wn + ni * 16 + col];

#pragma unroll
    for (int h2 = 0; h2 < 2; ++h2) {
        __syncthreads();                    // Shf free (prev half read / As reads done)
        if ((wv & 1) == h2) {               // waves owning rows [h2*64, h2*64+64)
#pragma unroll
            for (int ni = 0; ni < 4; ++ni) {
                int jloc = wn + ni * 16 + col;
#pragma unroll
                for (int mi = 0; mi < 4; ++mi) {
                    int rl = mi * 16 + quad * 4;     // local row 0..63
#pragma unroll
                    for (int r = 0; r < 4; ++r)
                        Shf[(rl + r) * 132 + jloc] = acc[mi][ni][r] + biasv[ni];
                }
            }
        }
        __syncthreads();
        // 4 threads per row; each stores 8 float4 (64B contiguous per 4-lane group)
        int row = t >> 2;                   // 0..63
        int m = m0 + h2 * 64 + row;
        float* ob = out + spatial_off(m) + n0 + (t & 3) * 4;
        const float* sb = Shf + row * 132 + (t & 3) * 4;
#pragma unroll
        for (int k = 0; k < 8; ++k)
            *(float4*)(ob + k * 16) = *(const float4*)(sb + k * 16);
    }
}

// ---------------- MFMA windowed attention v13: q-tile PAIRING ----------------
// v8 skeleton; each wave processes its 4 q-tiles as 2 PAIRS. Within a pair, the
// K fragment (QK A-operand) and V fragments (PV A-operand) are each read from
// LDS ONCE and feed both q-tiles' MFMAs -> kf+v LDS traffic per unit work
// halves (LDS pipe was ~30us of the 48us: 570 issue-cyc x 8 (qs,c) x 16 waves/CU).
// acc grouped 4 tiles at a time (accA[4]+accB[4]=32 regs; peak live ~95 < 128
// -> 4 waves/SIMD kept, no spill). MFMA count unchanged.
__global__ __launch_bounds__(512, 2) void attn_kernel(
    const ushort* __restrict__ Q, const ushort* __restrict__ K,
    const ushort* __restrict__ Vf, const uint* __restrict__ Up,
    ushort* __restrict__ Y) {
    __shared__ short Kl[512 * 32];       // QK A-fragment order (pre-permuted in global)
    __shared__ short Vs[64 * 256];       // PV A-fragment order (pre-permuted in global)
    __shared__ uint  Ul[3375];           // per-head rel-pos pair table (log2-scaled)

    const int t = threadIdx.x;
    const int bid = blockIdx.x;
    const int w = bid >> 3, head = bid & 7;
    const int wh = w >> 4, ww = (w >> 2) & 3, wd = w & 3;
    const int wv = t >> 6, lane = t & 63, quad = lane >> 4, col = lane & 15;

    const ushort* Kg = K + (size_t)(w * 8 + head) * 512 * 32;
    const ushort* Vg = Vf + (size_t)(w * 8 + head) * 512 * 32;
    const ushort* Qg = Q + (size_t)(w * 8 + head) * 512 * 32;

    // ---- stage K and V once (async direct-to-LDS, linear; 512 threads x 4 iters) ----
#pragma unroll
    for (int i = 0; i < 4; ++i) {
        gl_lds16(Kg + (size_t)(i * 512 + t) * 8, Kl + (i * 512 + wv * 64) * 8);
        gl_lds16(Vg + (size_t)(i * 512 + t) * 8, Vs + (i * 512 + wv * 64) * 8);
    }
    // ---- stage this head's pair table ----
    const uint* Uph = Up + head * 3375;
    for (int i = t; i < 3375; i += 512) Ul[i] = Uph[i];
    __syncthreads();

    const bool boundary = (wh == 3) | (ww == 3) | (wd == 3);
    floatx4 zf = {0.f, 0.f, 0.f, 0.f};

    for (int qp = 0; qp < 2; ++qp) {
        const int qtA = wv * 4 + qp * 2;
        const int qtB = qtA + 1;
        const short8 qfA = *(const short8*)(Qg + (size_t)(qtA * 16 + col) * 32 + quad * 8);
        const short8 qfB = *(const short8*)(Qg + (size_t)(qtB * 16 + col) * 32 + quad * 8);

        const int qrowA = qtA * 16 + col;
        const int qrowB = qtB * 16 + col;
        const int qhA = qrowA >> 6, qwA = (qrowA >> 3) & 7, qdA = qrowA & 7;
        const int qhB = qrowB >> 6, qwB = (qrowB >> 3) & 7, qdB = qrowB & 7;
        const int Base0A = ((qhA + 7) * 15 + (qwA + 7 - (quad >> 1))) * 15
                         + (qdA - ((quad & 1) << 2) + 7);
        const int Base0B = ((qhB + 7) * 15 + (qwB + 7 - (quad >> 1))) * 15
                         + (qdB - ((quad & 1) << 2) + 7);
        const int cqA = ((wh == 3) ? (1 + ((qrowA >> 8) & 1)) * 16 : 0)
                      + ((ww == 3) ? (1 + ((qrowA >> 5) & 1)) * 4 : 0)
                      + ((wd == 3) ? (1 + ((qrowA >> 2) & 1)) : 0);
        const int cqB = ((wh == 3) ? (1 + ((qrowB >> 8) & 1)) * 16 : 0)
                      + ((ww == 3) ? (1 + ((qrowB >> 5) & 1)) * 4 : 0)
                      + ((wd == 3) ? (1 + ((qrowB >> 2) & 1)) : 0);

        float rsA = 0.f, rsB = 0.f;
        floatx4 oA0 = zf, oA1 = zf, oB0 = zf, oB1 = zf;

        for (int c = 0; c < 2; ++c) {   // rolled: keeps register liveness low
            const short* KlC = Kl + c * 8192;
            const short* VsC = Vs + c * 8192;
            const int BaseCA = Base0A - c * 900;
            const int BaseCB = Base0B - c * 900;
            const int ckh = (wh == 3) ? ((1 + c) * 16) : 0;

            // 16 tiles in 4 groups of 4: kf read once per tile, feeds both q
            for (int g = 0; g < 4; ++g) {   // rolled: keeps liveness low
                floatx4 accA[4], accB[4];
#pragma unroll
                for (int tg = 0; tg < 4; ++tg) {
                    const int tt = g * 4 + tg;
                    const int Kt2 = ((tt >> 2) * 15 + (tt & 3) * 2) * 15;
                    float madd = 0.f;
                    int ckb = 0;
                    if (boundary) {
                        ckb = ckh
                            + ((ww == 3) ? (1 + ((tt >> 1) & 1)) * 4 : 0)
                            + ((wd == 3) ? (1 + (quad & 1)) : 0);
                    }
                    uint p0A = Ul[BaseCA - Kt2];
                    uint p1A = Ul[BaseCA - Kt2 - 2];
                    floatx4 cfA;
                    cfA[0] = __uint_as_float(p0A << 16);
                    cfA[1] = __uint_as_float(p0A & 0xffff0000u);
                    cfA[2] = __uint_as_float(p1A << 16);
                    cfA[3] = __uint_as_float(p1A & 0xffff0000u);
                    uint p0B = Ul[BaseCB - Kt2];
                    uint p1B = Ul[BaseCB - Kt2 - 2];
                    floatx4 cfB;
                    cfB[0] = __uint_as_float(p0B << 16);
                    cfB[1] = __uint_as_float(p0B & 0xffff0000u);
                    cfB[2] = __uint_as_float(p1B << 16);
                    cfB[3] = __uint_as_float(p1B & 0xffff0000u);
                    if (boundary) {
                        float mA = (cqA == ckb) ? 0.f : -144.269504f;  // -100*log2e
                        float mB = (cqB == ckb) ? 0.f : -144.269504f;
                        cfA[0] += mA; cfA[1] += mA; cfA[2] += mA; cfA[3] += mA;
                        cfB[0] += mB; cfB[1] += mB; cfB[2] += mB; cfB[3] += mB;
                    }
                    (void)madd;
                    short8 kf = *(const short8*)(KlC + tt * 512 + lane * 8);
                    accA[tg] = __builtin_amdgcn_mfma_f32_16x16x32_bf16(kf, qfA, cfA, 0, 0, 0);
                    accB[tg] = __builtin_amdgcn_mfma_f32_16x16x32_bf16(kf, qfB, cfB, 0, 0, 0);
                }

                // consume: v0/v1 read once, feed both q-tiles' PV MFMAs
#pragma unroll
                for (int tg = 0; tg < 4; ++tg) {
                    const int tt = g * 4 + tg;
                    float eA0 = __builtin_amdgcn_exp2f(accA[tg][0]);
                    float eA1 = __builtin_amdgcn_exp2f(accA[tg][1]);
                    float eA2 = __builtin_amdgcn_exp2f(accA[tg][2]);
                    float eA3 = __builtin_amdgcn_exp2f(accA[tg][3]);
                    rsA += (eA0 + eA1) + (eA2 + eA3);
                    float eB0 = __builtin_amdgcn_exp2f(accB[tg][0]);
                    float eB1 = __builtin_amdgcn_exp2f(accB[tg][1]);
                    float eB2 = __builtin_amdgcn_exp2f(accB[tg][2]);
                    float eB3 = __builtin_amdgcn_exp2f(accB[tg][3]);
                    rsB += (eB0 + eB1) + (eB2 + eB3);
                    uint2v ppA, ppB;
                    ppA[0] = pk2bf(eA0, eA1);
                    ppA[1] = pk2bf(eA2, eA3);
                    ppB[0] = pk2bf(eB0, eB1);
                    ppB[1] = pk2bf(eB2, eB3);
                    s4v pfA = __builtin_bit_cast(s4v, ppA);
                    s4v pfB = __builtin_bit_cast(s4v, ppB);
                    s4v v0 = *(const s4v*)(VsC + ((tt * 2 + 0) << 8) + lane * 4);
                    s4v v1 = *(const s4v*)(VsC + ((tt * 2 + 1) << 8) + lane * 4);
                    oA0 = __builtin_amdgcn_mfma_f32_16x16x16bf16_1k(v0, pfA, oA0, 0, 0, 0);
                    oB0 = __builtin_amdgcn_mfma_f32_16x16x16bf16_1k(v0, pfB, oB0, 0, 0, 0);
                    oA1 = __builtin_amdgcn_mfma_f32_16x16x16bf16_1k(v1, pfA, oA1, 0, 0, 0);
                    oB1 = __builtin_amdgcn_mfma_f32_16x16x16bf16_1k(v1, pfB, oB1, 0, 0, 0);
                }
            }
        }

        // ---- epilogue x2: O^T row=hd(quad*4+r), col=q(lane&15) ----
        {
            float r = rsA;
            r += __shfl_xor(r, 16);
            r += __shfl_xor(r, 32);
            const float inv = __builtin_amdgcn_rcpf(r);
            int token = w * 512 + qtA * 16 + col;
            ushort* Yb = Y + (size_t)token * 256 + head * 32 + quad * 4;
            uint2v y0, y1;
            y0[0] = pk2bf(oA0[0] * inv, oA0[1] * inv);
            y0[1] = pk2bf(oA0[2] * inv, oA0[3] * inv);
            y1[0] = pk2bf(oA1[0] * inv, oA1[1] * inv);
            y1[1] = pk2bf(oA1[2] * inv, oA1[3] * inv);
            *(uint2v*)(Yb) = y0;
            *(uint2v*)(Yb + 16) = y1;
        }
        {
            float r = rsB;
            r += __shfl_xor(r, 16);
            r += __shfl_xor(r, 32);
            const float inv = __builtin_amdgcn_rcpf(r);
            int token = w * 512 + qtB * 16 + col;
            ushort* Yb = Y + (size_t)token * 256 + head * 32 + quad * 4;
            uint2v y0, y1;
            y0[0] = pk2bf(oB0[0] * inv, oB0[1] * inv);
            y0[1] = pk2bf(oB0[2] * inv, oB0[3] * inv);
            y1[0] = pk2bf(oB1[0] * inv, oB1[1] * inv);
            y1[1] = pk2bf(oB1[2] * inv, oB1[3] * inv);
            *(uint2v*)(Yb) = y0;
            *(uint2v*)(Yb + 16) = y1;
        }
    }
}

extern "C" void kernel_launch(void* const* d_in, const int* in_sizes, int n_in,
                              void* d_out, int out_size, void* d_ws, size_t ws_size,
                              hipStream_t stream) {
    const float* x      = (const float*)d_in[0];
    const float* qkv_w  = (const float*)d_in[1];
    const float* qkv_b  = (const float*)d_in[2];
    const float* proj_w = (const float*)d_in[3];
    const float* proj_b = (const float*)d_in[4];
    const float* rpb    = (const float*)d_in[5];
    float* out = (float*)d_out;

    // ws layout (ushorts): Xw 8.39M | Q 8.39M | K 8.39M | Vf 8.39M | Y 8.39M | Up 54K | Wqb | Wpb
    ushort* Xw  = (ushort*)d_ws;
    ushort* Q   = Xw + 8388608;
    ushort* K   = Q + 8388608;
    ushort* Vf  = K + 8388608;
    ushort* Y   = Vf + 8388608;
    uint*   Up  = (uint*)(Y + 8388608);
    ushort* Wqb = (ushort*)(Up + 27008);
    ushort* Wpb = Wqb + 196608;

    prep<<<dim3(5226), dim3(256), 0, stream>>>(x, qkv_w, proj_w, rpb, Xw, Wqb, Wpb, Up);
    gemm_qkv<<<dim3(6, 256), dim3(256), 0, stream>>>(Xw, Wqb, qkv_b, Q, K, Vf);
    attn_kernel<<<dim3(512), dim3(512), 0, stream>>>(Q, K, Vf, Up, Y);
    gemm_proj<<<dim3(2, 256), dim3(256), 0, stream>>>(Y, Wpb, proj_b, out);
}

// Round 13
// 174.710 us; speedup vs baseline: 1.2236x; 1.2236x over previous
//
#include <hip/hip_runtime.h>

typedef __attribute__((ext_vector_type(8))) short short8;
typedef __attribute__((ext_vector_type(4))) short s4v;
typedef __attribute__((ext_vector_type(2))) uint uint2v;
typedef __attribute__((ext_vector_type(4))) uint uint4v;
typedef __attribute__((ext_vector_type(4))) float floatx4;

#define CCH   256
#define QSCALE 0.17677669529663687f  // 32^-0.5
#define LOG2E  1.4426950408889634f

__device__ __forceinline__ unsigned short f2bf(float f) {
    unsigned u = __float_as_uint(f);
    u = u + 0x7fffu + ((u >> 16) & 1u);
    return (unsigned short)(u >> 16);
}

// pack two fp32 -> bf16x2 with round-half-up: (u+0x8000)>>16, fused via v_perm
__device__ __forceinline__ uint pk2bf(float a, float b) {
    uint ua = __float_as_uint(a) + 0x8000u;
    uint ub = __float_as_uint(b) + 0x8000u;
    return __builtin_amdgcn_perm(ub, ua, 0x07060302u);
}

__device__ __forceinline__ void gl_lds16(const void* g, void* l) {
    __builtin_amdgcn_global_load_lds((const __attribute__((address_space(1))) void*)g,
                                     (__attribute__((address_space(3))) void*)l, 16, 0, 0);
}

// token (w*512+n) -> flat spatial offset (*CCH) in x/out with +4 cyclic shift
__device__ __forceinline__ int spatial_off(int token) {
    int w = token >> 9, n = token & 511;
    int wh = w >> 4, ww = (w >> 2) & 3, wd = w & 3;
    int h1 = n >> 6, w1 = (n >> 3) & 7, d1 = n & 7;
    int gh = (wh * 8 + h1 + 4) & 31;
    int gw = (ww * 8 + w1 + 4) & 31;
    int gd = (wd * 8 + d1 + 4) & 31;
    return ((gh * 32 + gw) * 32 + gd) * CCH;
}

// ---------------- fused preprocessing: xconv | wconv | pair_prep ----------------
__global__ __launch_bounds__(256) void prep(const float* __restrict__ x,
                                            const float* __restrict__ Wq,
                                            const float* __restrict__ Wp,
                                            const float* __restrict__ rpb,
                                            ushort* __restrict__ Xw,
                                            ushort* __restrict__ Wqb,
                                            ushort* __restrict__ Wpb,
                                            uint* __restrict__ Up) {
    int b = blockIdx.x;
    if (b < 4096) {
        int tid = b * 256 + threadIdx.x;   // 1048576
        int token = tid >> 5, c8 = (tid & 31) * 8;
        const float* src = x + spatial_off(token) + c8;
        float4 a = *(const float4*)src;
        float4 bb = *(const float4*)(src + 4);
        uint2v lo, hi;
        lo[0] = pk2bf(a.x, a.y);
        lo[1] = pk2bf(a.z, a.w);
        hi[0] = pk2bf(bb.x, bb.y);
        hi[1] = pk2bf(bb.z, bb.w);
        uint2v* dst = (uint2v*)(Xw + (size_t)token * 256 + c8);
        dst[0] = lo;
        dst[1] = hi;
    } else if (b < 5120) {
        int tid = (b - 4096) * 256 + threadIdx.x;   // 262144
        if (tid < 196608) {
            float s = (tid < 65536) ? (QSCALE * LOG2E) : 1.0f;
            Wqb[tid] = f2bf(Wq[tid] * s);
        } else {
            int i = tid - 196608;
            Wpb[i] = f2bf(Wp[i]);
        }
    } else {
        int tid = (b - 5120) * 256 + threadIdx.x;   // 27000
        if (tid >= 27000) return;
        int head = tid / 3375, idx = tid - head * 3375;
        uint lo = f2bf(rpb[idx * 8 + head] * LOG2E);
        uint hi = f2bf(rpb[(idx > 0 ? idx - 1 : 0) * 8 + head] * LOG2E);
        Up[tid] = lo | (hi << 16);
    }
}

// ---------------- MFMA GEMM: C[32768 x 768] = Xw @ Wqb^T -> Q/K/Vf ----------------
// V in K=16 A-fragment order; K in K=32 QK A-fragment order; Q row-major.
// Q/K epilogue: LDS-bounce transpose -> coalesced 16B packed stores.
__global__ __launch_bounds__(256) void gemm_qkv(
    const ushort* __restrict__ A,   // [32768][256] bf16
    const ushort* __restrict__ Bw,  // [768][256] bf16
    const float* __restrict__ bq,
    ushort* __restrict__ Q, ushort* __restrict__ K, ushort* __restrict__ Vf) {
    __shared__ short Sh[17408];     // main loop: As=Sh[0:8192], Bs=Sh[8192:16384]
                                    // epilogue:  128x136 bf16 tile (rows 16B-aligned)
    short* As = Sh;
    short* Bs = Sh + 8192;
    const int t = threadIdx.x;
    const int wv = t >> 6, lane = t & 63, quad = lane >> 4, col = lane & 15;
    const int m0 = blockIdx.y * 128, n0 = blockIdx.x * 128;
    const int wm = (wv & 1) * 64, wn = (wv >> 1) * 64;

    floatx4 zf = {0.f, 0.f, 0.f, 0.f};
    floatx4 acc[4][4];
#pragma unroll
    for (int i = 0; i < 4; ++i)
#pragma unroll
        for (int j = 0; j < 4; ++j) acc[i][j] = zf;

    for (int kk = 0; kk < 256; kk += 64) {
        __syncthreads();
#pragma unroll
        for (int i = 0; i < 4; ++i) {
            int s = i * 256 + t;
            int row = s >> 3, qs = s & 7;
            int qg = qs ^ (row & 7);
            gl_lds16(A + (size_t)(m0 + row) * 256 + kk + qg * 8,
                     As + (i * 256 + wv * 64) * 8);
        }
#pragma unroll
        for (int i = 0; i < 4; ++i) {
            int s = i * 256 + t;
            int row = s >> 3, qs = s & 7;
            int qg = qs ^ (row & 7);
            gl_lds16(Bw + (size_t)(n0 + row) * 256 + kk + qg * 8,
                     Bs + (i * 256 + wv * 64) * 8);
        }
        __syncthreads();
#pragma unroll
        for (int h = 0; h < 2; ++h) {
            short8 af[4], bf[4];
#pragma unroll
            for (int mi = 0; mi < 4; ++mi) {
                int row = wm + mi * 16 + col;
                af[mi] = *(const short8*)(As + (row * 8 + ((h * 4 + quad) ^ (row & 7))) * 8);
            }
#pragma unroll
            for (int ni = 0; ni < 4; ++ni) {
                int row = wn + ni * 16 + col;
                bf[ni] = *(const short8*)(Bs + (row * 8 + ((h * 4 + quad) ^ (row & 7))) * 8);
            }
#pragma unroll
            for (int mi = 0; mi < 4; ++mi)
#pragma unroll
                for (int ni = 0; ni < 4; ++ni)
                    acc[mi][ni] = __builtin_amdgcn_mfma_f32_16x16x32_bf16(af[mi], bf[ni], acc[mi][ni], 0, 0, 0);
        }
    }

    const int bx = blockIdx.x;   // 0,1: Q   2,3: K   4,5: V  (block-uniform)
    if (bx >= 4) {
        // ---- V: direct packed stores (fragment order already n-contiguous) ----
#pragma unroll
        for (int ni = 0; ni < 4; ++ni) {
            int j = n0 + wn + ni * 16 + col;
            int head = (j >> 5) & 7, hd = j & 31;
            float bias = bq[j];
            int h = hd >> 4, colv = hd & 15;
#pragma unroll
            for (int mi = 0; mi < 4; ++mi) {
                int mb = m0 + wm + mi * 16 + quad * 4;   // n&3 = r, contiguous
                int w = mb >> 9, n = mb & 511;
                size_t off = ((size_t)((w * 8 + head) * 64 + (n >> 4) * 2 + h) << 8)
                           + ((((n >> 2) & 3) * 16 + colv) << 2);
                uint2v pv;
                pv[0] = pk2bf(acc[mi][ni][0] + bias, acc[mi][ni][1] + bias);
                pv[1] = pk2bf(acc[mi][ni][2] + bias, acc[mi][ni][3] + bias);
                *(uint2v*)(Vf + off) = pv;
            }
        }
    } else {
        // ---- Q/K: LDS-bounce -> 8 coalesced 16B stores/thread ----
        __syncthreads();   // all waves done reading As/Bs
#pragma unroll
        for (int ni = 0; ni < 4; ++ni) {
            int j = n0 + wn + ni * 16 + col;
            int jloc = wn + ni * 16 + col;
            float bias = bq[j] * ((j < 256) ? (QSCALE * LOG2E) : 1.0f);
#pragma unroll
            for (int mi = 0; mi < 4; ++mi) {
                int rowb = wm + mi * 16 + quad * 4;
#pragma unroll
                for (int r = 0; r < 4; ++r)
                    Sh[(rowb + r) * 136 + jloc] = (short)f2bf(acc[mi][ni][r] + bias);
            }
        }
        __syncthreads();
        ushort* dst = (bx < 2) ? Q : K;
#pragma unroll
        for (int k8 = 0; k8 < 8; ++k8) {
            int chunk = k8 * 256 + t;        // 0..2047
            int row = chunk >> 4;            // 0..127
            int jl = (chunk & 15) * 8;       // 0..120
            int j = n0 + jl;
            int m = m0 + row;
            int w = m >> 9, n = m & 511;
            int head = (j >> 5) & 7, hd = j & 31;
            uint4v vv = *(const uint4v*)(Sh + row * 136 + jl);
            size_t off;
            if (bx < 2) {
                off = ((size_t)(w * 8 + head) * 512 + n) * 32 + hd;          // row-major
            } else {
                off = ((size_t)(w * 8 + head) << 14) + ((size_t)(n >> 4) << 9)
                    + (((hd >> 3) * 16 + (n & 15)) << 3);                    // frag order
            }
            *(uint4v*)(dst + off) = vv;
        }
    }
}

// ---------------- MFMA GEMM: out = Y @ Wpb^T + bp, scatter w/ reverse shift ----------
// Epilogue: LDS-bounce (2 half-tiles of 64 rows, 64x132 f32) -> coalesced dwordx4.
__global__ __launch_bounds__(256) void gemm_proj(
    const ushort* __restrict__ A,   // Y [32768][256] bf16
    const ushort* __restrict__ Bw,  // [256][256] bf16
    const float* __restrict__ bp,
    float* __restrict__ out) {
    __shared__ short As[128 * 64];
    __shared__ short Bs[128 * 64];
    __shared__ float Shf[64 * 132];  // 33KB bounce buffer (separate; total 65KB, 2/CU)
    const int t = threadIdx.x;
    const int wv = t >> 6, lane = t & 63, quad = lane >> 4, col = lane & 15;
    const int m0 = blockIdx.y * 128, n0 = blockIdx.x * 128;
    const int wm = (wv & 1) * 64, wn = (wv >> 1) * 64;

    floatx4 zf = {0.f, 0.f, 0.f, 0.f};
    floatx4 acc[4][4];
#pragma unroll
    for (int i = 0; i < 4; ++i)
#pragma unroll
        for (int j = 0; j < 4; ++j) acc[i][j] = zf;

    for (int kk = 0; kk < 256; kk += 64) {
        __syncthreads();
#pragma unroll
        for (int i = 0; i < 4; ++i) {
            int s = i * 256 + t;
            int row = s >> 3, qs = s & 7;
            int qg = qs ^ (row & 7);
            gl_lds16(A + (size_t)(m0 + row) * 256 + kk + qg * 8,
                     As + (i * 256 + wv * 64) * 8);
        }
#pragma unroll
        for (int i = 0; i < 4; ++i) {
            int s = i * 256 + t;
            int row = s >> 3, qs = s & 7;
            int qg = qs ^ (row & 7);
            gl_lds16(Bw + (size_t)(n0 + row) * 256 + kk + qg * 8,
                     Bs + (i * 256 + wv * 64) * 8);
        }
        __syncthreads();
#pragma unroll
        for (int h = 0; h < 2; ++h) {
            short8 af[4], bf[4];
#pragma unroll
            for (int mi = 0; mi < 4; ++mi) {
                int row = wm + mi * 16 + col;
                af[mi] = *(const short8*)(As + (row * 8 + ((h * 4 + quad) ^ (row & 7))) * 8);
            }
#pragma unroll
            for (int ni = 0; ni < 4; ++ni) {
                int row = wn + ni * 16 + col;
                bf[ni] = *(const short8*)(Bs + (row * 8 + ((h * 4 + quad) ^ (row & 7))) * 8);
            }
#pragma unroll
            for (int mi = 0; mi < 4; ++mi)
#pragma unroll
                for (int ni = 0; ni < 4; ++ni)
                    acc[mi][ni] = __builtin_amdgcn_mfma_f32_16x16x32_bf16(af[mi], bf[ni], acc[mi][ni], 0, 0, 0);
        }
    }

    // ---- epilogue: bounce 2 half-tiles (64 rows x 128 f32) through Shf ----
    float biasv[4];
#pragma unroll
    for (int ni = 0; ni < 4; ++ni) biasv[ni] = bp[n0 + wn + ni * 16 + col];

#pragma unroll
    for (int h2 = 0; h2 < 2; ++h2) {
        __syncthreads();                    // Shf free (prev half read / As reads done)
        if ((wv & 1) == h2) {               // waves owning rows [h2*64, h2*64+64)
#pragma unroll
            for (int ni = 0; ni < 4; ++ni) {
                int jloc = wn + ni * 16 + col;
#pragma unroll
                for (int mi = 0; mi < 4; ++mi) {
                    int rl = mi * 16 + quad * 4;     // local row 0..63
#pragma unroll
                    for (int r = 0; r < 4; ++r)
                        Shf[(rl + r) * 132 + jloc] = acc[mi][ni][r] + biasv[ni];
                }
            }
        }
        __syncthreads();
        // 4 threads per row; each stores 8 float4 (64B contiguous per 4-lane group)
        int row = t >> 2;                   // 0..63
        int m = m0 + h2 * 64 + row;
        float* ob = out + spatial_off(m) + n0 + (t & 3) * 4;
        const float* sb = Shf + row * 132 + (t & 3) * 4;
#pragma unroll
        for (int k = 0; k < 8; ++k)
            *(float4*)(ob + k * 16) = *(const float4*)(sb + k * 16);
    }
}

// ---------------- MFMA windowed attention v14: fused-per-tile q-PAIRING ----------------
// v8 skeleton + q-tile pairing with MINIMAL live set: no acc arrays; each tile tt
// fuses produce+consume (kf read once -> 2 QK MFMAs -> exp/pack both -> v0/v1
// read once -> 4 PV MFMAs). kf+v LDS traffic per unit work halves (LDS pipe was
// ~30us of 48us). Transient ~32 regs + persistent ~52 -> ~85 total, under the
// 128 step. v13's accA[4]/accB[4] grouped arrays spilled (128 VGPR, WRITE 113MB);
// this form gives the RA the same sequential structure it pipelines to 56 in v8.
__global__ __launch_bounds__(512, 2) void attn_kernel(
    const ushort* __restrict__ Q, const ushort* __restrict__ K,
    const ushort* __restrict__ Vf, const uint* __restrict__ Up,
    ushort* __restrict__ Y) {
    __shared__ short Kl[512 * 32];       // QK A-fragment order (pre-permuted in global)
    __shared__ short Vs[64 * 256];       // PV A-fragment order (pre-permuted in global)
    __shared__ uint  Ul[3375];           // per-head rel-pos pair table (log2-scaled)

    const int t = threadIdx.x;
    const int bid = blockIdx.x;
    const int w = bid >> 3, head = bid & 7;
    const int wh = w >> 4, ww = (w >> 2) & 3, wd = w & 3;
    const int wv = t >> 6, lane = t & 63, quad = lane >> 4, col = lane & 15;

    const ushort* Kg = K + (size_t)(w * 8 + head) * 512 * 32;
    const ushort* Vg = Vf + (size_t)(w * 8 + head) * 512 * 32;
    const ushort* Qg = Q + (size_t)(w * 8 + head) * 512 * 32;

    // ---- stage K and V once (async direct-to-LDS, linear; 512 threads x 4 iters) ----
#pragma unroll
    for (int i = 0; i < 4; ++i) {
        gl_lds16(Kg + (size_t)(i * 512 + t) * 8, Kl + (i * 512 + wv * 64) * 8);
        gl_lds16(Vg + (size_t)(i * 512 + t) * 8, Vs + (i * 512 + wv * 64) * 8);
    }
    // ---- stage this head's pair table ----
    const uint* Uph = Up + head * 3375;
    for (int i = t; i < 3375; i += 512) Ul[i] = Uph[i];
    __syncthreads();

    const bool boundary = (wh == 3) | (ww == 3) | (wd == 3);
    floatx4 zf = {0.f, 0.f, 0.f, 0.f};

    for (int qp = 0; qp < 2; ++qp) {
        const int qtA = wv * 4 + qp * 2;
        const int qtB = qtA + 1;
        const short8 qfA = *(const short8*)(Qg + (size_t)(qtA * 16 + col) * 32 + quad * 8);
        const short8 qfB = *(const short8*)(Qg + (size_t)(qtB * 16 + col) * 32 + quad * 8);

        const int qrowA = qtA * 16 + col;
        const int qrowB = qtB * 16 + col;
        const int qhA = qrowA >> 6, qwA = (qrowA >> 3) & 7, qdA = qrowA & 7;
        const int qhB = qrowB >> 6, qwB = (qrowB >> 3) & 7, qdB = qrowB & 7;
        const int Base0A = ((qhA + 7) * 15 + (qwA + 7 - (quad >> 1))) * 15
                         + (qdA - ((quad & 1) << 2) + 7);
        const int Base0B = ((qhB + 7) * 15 + (qwB + 7 - (quad >> 1))) * 15
                         + (qdB - ((quad & 1) << 2) + 7);
        const int cqA = ((wh == 3) ? (1 + ((qrowA >> 8) & 1)) * 16 : 0)
                      + ((ww == 3) ? (1 + ((qrowA >> 5) & 1)) * 4 : 0)
                      + ((wd == 3) ? (1 + ((qrowA >> 2) & 1)) : 0);
        const int cqB = ((wh == 3) ? (1 + ((qrowB >> 8) & 1)) * 16 : 0)
                      + ((ww == 3) ? (1 + ((qrowB >> 5) & 1)) * 4 : 0)
                      + ((wd == 3) ? (1 + ((qrowB >> 2) & 1)) : 0);

        float rsA = 0.f, rsB = 0.f;
        floatx4 oA0 = zf, oA1 = zf, oB0 = zf, oB1 = zf;

        for (int c = 0; c < 2; ++c) {   // rolled: keeps register liveness low
            const short* KlC = Kl + c * 8192;
            const short* VsC = Vs + c * 8192;
            const int BaseCA = Base0A - c * 900;
            const int BaseCB = Base0B - c * 900;
            const int ckh = (wh == 3) ? ((1 + c) * 16) : 0;

#pragma unroll 4
            for (int tt = 0; tt < 16; ++tt) {
                const int Kt2 = ((tt >> 2) * 15 + (tt & 3) * 2) * 15;
                // bias (and mask) preloaded into the MFMA C operands
                uint p0A = Ul[BaseCA - Kt2];
                uint p1A = Ul[BaseCA - Kt2 - 2];
                uint p0B = Ul[BaseCB - Kt2];
                uint p1B = Ul[BaseCB - Kt2 - 2];
                floatx4 cfA, cfB;
                cfA[0] = __uint_as_float(p0A << 16);
                cfA[1] = __uint_as_float(p0A & 0xffff0000u);
                cfA[2] = __uint_as_float(p1A << 16);
                cfA[3] = __uint_as_float(p1A & 0xffff0000u);
                cfB[0] = __uint_as_float(p0B << 16);
                cfB[1] = __uint_as_float(p0B & 0xffff0000u);
                cfB[2] = __uint_as_float(p1B << 16);
                cfB[3] = __uint_as_float(p1B & 0xffff0000u);
                if (boundary) {
                    int ckb = ckh
                            + ((ww == 3) ? (1 + ((tt >> 1) & 1)) * 4 : 0)
                            + ((wd == 3) ? (1 + (quad & 1)) : 0);
                    float mA = (cqA == ckb) ? 0.f : -144.269504f;  // -100*log2e
                    float mB = (cqB == ckb) ? 0.f : -144.269504f;
                    cfA[0] += mA; cfA[1] += mA; cfA[2] += mA; cfA[3] += mA;
                    cfB[0] += mB; cfB[1] += mB; cfB[2] += mB; cfB[3] += mB;
                }
                // kf read ONCE, feeds both q-tiles' QK MFMAs
                short8 kf = *(const short8*)(KlC + tt * 512 + lane * 8);
                floatx4 sA = __builtin_amdgcn_mfma_f32_16x16x32_bf16(kf, qfA, cfA, 0, 0, 0);
                floatx4 sB = __builtin_amdgcn_mfma_f32_16x16x32_bf16(kf, qfB, cfB, 0, 0, 0);

                // consume immediately (no acc arrays)
                float eA0 = __builtin_amdgcn_exp2f(sA[0]);
                float eA1 = __builtin_amdgcn_exp2f(sA[1]);
                float eA2 = __builtin_amdgcn_exp2f(sA[2]);
                float eA3 = __builtin_amdgcn_exp2f(sA[3]);
                rsA += (eA0 + eA1) + (eA2 + eA3);
                float eB0 = __builtin_amdgcn_exp2f(sB[0]);
                float eB1 = __builtin_amdgcn_exp2f(sB[1]);
                float eB2 = __builtin_amdgcn_exp2f(sB[2]);
                float eB3 = __builtin_amdgcn_exp2f(sB[3]);
                rsB += (eB0 + eB1) + (eB2 + eB3);
                uint2v ppA, ppB;
                ppA[0] = pk2bf(eA0, eA1);
                ppA[1] = pk2bf(eA2, eA3);
                ppB[0] = pk2bf(eB0, eB1);
                ppB[1] = pk2bf(eB2, eB3);
                s4v pfA = __builtin_bit_cast(s4v, ppA);
                s4v pfB = __builtin_bit_cast(s4v, ppB);
                // v0/v1 read ONCE, feed both q-tiles' PV MFMAs
                s4v v0 = *(const s4v*)(VsC + ((tt * 2 + 0) << 8) + lane * 4);
                s4v v1 = *(const s4v*)(VsC + ((tt * 2 + 1) << 8) + lane * 4);
                oA0 = __builtin_amdgcn_mfma_f32_16x16x16bf16_1k(v0, pfA, oA0, 0, 0, 0);
                oB0 = __builtin_amdgcn_mfma_f32_16x16x16bf16_1k(v0, pfB, oB0, 0, 0, 0);
                oA1 = __builtin_amdgcn_mfma_f32_16x16x16bf16_1k(v1, pfA, oA1, 0, 0, 0);
                oB1 = __builtin_amdgcn_mfma_f32_16x16x16bf16_1k(v1, pfB, oB1, 0, 0, 0);
            }
        }

        // ---- epilogue x2: O^T row=hd(quad*4+r), col=q(lane&15) ----
        {
            float r = rsA;
            r += __shfl_xor(r, 16);
            r += __shfl_xor(r, 32);
            const float inv = __builtin_amdgcn_rcpf(r);
            int token = w * 512 + qtA * 16 + col;
            ushort* Yb = Y + (size_t)token * 256 + head * 32 + quad * 4;
            uint2v y0, y1;
            y0[0] = pk2bf(oA0[0] * inv, oA0[1] * inv);
            y0[1] = pk2bf(oA0[2] * inv, oA0[3] * inv);
            y1[0] = pk2bf(oA1[0] * inv, oA1[1] * inv);
            y1[1] = pk2bf(oA1[2] * inv, oA1[3] * inv);
            *(uint2v*)(Yb) = y0;
            *(uint2v*)(Yb + 16) = y1;
        }
        {
            float r = rsB;
            r += __shfl_xor(r, 16);
            r += __shfl_xor(r, 32);
            const float inv = __builtin_amdgcn_rcpf(r);
            int token = w * 512 + qtB * 16 + col;
            ushort* Yb = Y + (size_t)token * 256 + head * 32 + quad * 4;
            uint2v y0, y1;
            y0[0] = pk2bf(oB0[0] * inv, oB0[1] * inv);
            y0[1] = pk2bf(oB0[2] * inv, oB0[3] * inv);
            y1[0] = pk2bf(oB1[0] * inv, oB1[1] * inv);
            y1[1] = pk2bf(oB1[2] * inv, oB1[3] * inv);
            *(uint2v*)(Yb) = y0;
            *(uint2v*)(Yb + 16) = y1;
        }
    }
}

extern "C" void kernel_launch(void* const* d_in, const int* in_sizes, int n_in,
                              void* d_out, int out_size, void* d_ws, size_t ws_size,
                              hipStream_t stream) {
    const float* x      = (const float*)d_in[0];
    const float* qkv_w  = (const float*)d_in[1];
    const float* qkv_b  = (const float*)d_in[2];
    const float* proj_w = (const float*)d_in[3];
    const float* proj_b = (const float*)d_in[4];
    const float* rpb    = (const float*)d_in[5];
    float* out = (float*)d_out;

    // ws layout (ushorts): Xw 8.39M | Q 8.39M | K 8.39M | Vf 8.39M | Y 8.39M | Up 54K | Wqb | Wpb
    ushort* Xw  = (ushort*)d_ws;
    ushort* Q   = Xw + 8388608;
    ushort* K   = Q + 8388608;
    ushort* Vf  = K + 8388608;
    ushort* Y   = Vf + 8388608;
    uint*   Up  = (uint*)(Y + 8388608);
    ushort* Wqb = (ushort*)(Up + 27008);
    ushort* Wpb = Wqb + 196608;

    prep<<<dim3(5226), dim3(256), 0, stream>>>(x, qkv_w, proj_w, rpb, Xw, Wqb, Wpb, Up);
    gemm_qkv<<<dim3(6, 256), dim3(256), 0, stream>>>(Xw, Wqb, qkv_b, Q, K, Vf);
    attn_kernel<<<dim3(512), dim3(512), 0, stream>>>(Q, K, Vf, Up, Y);
    gemm_proj<<<dim3(2, 256), dim3(256), 0, stream>>>(Y, Wpb, proj_b, out);
}

// Round 14
// 171.199 us; speedup vs baseline: 1.2487x; 1.0205x over previous
//
#include <hip/hip_runtime.h>

typedef __attribute__((ext_vector_type(8))) short short8;
typedef __attribute__((ext_vector_type(4))) short s4v;
typedef __attribute__((ext_vector_type(2))) uint uint2v;
typedef __attribute__((ext_vector_type(4))) uint uint4v;
typedef __attribute__((ext_vector_type(4))) float floatx4;

#define CCH   256
#define QSCALE 0.17677669529663687f  // 32^-0.5
#define LOG2E  1.4426950408889634f

__device__ __forceinline__ unsigned short f2bf(float f) {
    unsigned u = __float_as_uint(f);
    u = u + 0x7fffu + ((u >> 16) & 1u);
    return (unsigned short)(u >> 16);
}

// pack two fp32 -> bf16x2 with round-half-up: (u+0x8000)>>16, fused via v_perm
__device__ __forceinline__ uint pk2bf(float a, float b) {
    uint ua = __float_as_uint(a) + 0x8000u;
    uint ub = __float_as_uint(b) + 0x8000u;
    return __builtin_amdgcn_perm(ub, ua, 0x07060302u);
}

__device__ __forceinline__ void gl_lds16(const void* g, void* l) {
    __builtin_amdgcn_global_load_lds((const __attribute__((address_space(1))) void*)g,
                                     (__attribute__((address_space(3))) void*)l, 16, 0, 0);
}

// token (w*512+n) -> flat spatial offset (*CCH) in x/out with +4 cyclic shift
__device__ __forceinline__ int spatial_off(int token) {
    int w = token >> 9, n = token & 511;
    int wh = w >> 4, ww = (w >> 2) & 3, wd = w & 3;
    int h1 = n >> 6, w1 = (n >> 3) & 7, d1 = n & 7;
    int gh = (wh * 8 + h1 + 4) & 31;
    int gw = (ww * 8 + w1 + 4) & 31;
    int gd = (wd * 8 + d1 + 4) & 31;
    return ((gh * 32 + gw) * 32 + gd) * CCH;
}

// ---------------- fused preprocessing: xconv | wconv | pair_prep ----------------
__global__ __launch_bounds__(256) void prep(const float* __restrict__ x,
                                            const float* __restrict__ Wq,
                                            const float* __restrict__ Wp,
                                            const float* __restrict__ rpb,
                                            ushort* __restrict__ Xw,
                                            ushort* __restrict__ Wqb,
                                            ushort* __restrict__ Wpb,
                                            uint* __restrict__ Up) {
    int b = blockIdx.x;
    if (b < 4096) {
        int tid = b * 256 + threadIdx.x;   // 1048576
        int token = tid >> 5, c8 = (tid & 31) * 8;
        const float* src = x + spatial_off(token) + c8;
        float4 a = *(const float4*)src;
        float4 bb = *(const float4*)(src + 4);
        uint2v lo, hi;
        lo[0] = pk2bf(a.x, a.y);
        lo[1] = pk2bf(a.z, a.w);
        hi[0] = pk2bf(bb.x, bb.y);
        hi[1] = pk2bf(bb.z, bb.w);
        uint2v* dst = (uint2v*)(Xw + (size_t)token * 256 + c8);
        dst[0] = lo;
        dst[1] = hi;
    } else if (b < 5120) {
        int tid = (b - 4096) * 256 + threadIdx.x;   // 262144
        if (tid < 196608) {
            float s = (tid < 65536) ? (QSCALE * LOG2E) : 1.0f;
            Wqb[tid] = f2bf(Wq[tid] * s);
        } else {
            int i = tid - 196608;
            Wpb[i] = f2bf(Wp[i]);
        }
    } else {
        int tid = (b - 5120) * 256 + threadIdx.x;   // 27000
        if (tid >= 27000) return;
        int head = tid / 3375, idx = tid - head * 3375;
        uint lo = f2bf(rpb[idx * 8 + head] * LOG2E);
        uint hi = f2bf(rpb[(idx > 0 ? idx - 1 : 0) * 8 + head] * LOG2E);
        Up[tid] = lo | (hi << 16);
    }
}

// ---------------- MFMA GEMM: C[32768 x 768] = Xw @ Wqb^T -> Q/K/Vf ----------------
// V in K=16 A-fragment order; K in K=32 QK A-fragment order; Q row-major.
// 2-phase double-buffered staging (T3 minimum): issue STAGE(next) before
// computing current; one barrier per K-tile -> HBM/L2 latency hidden under MFMA.
// Q/K epilogue: LDS-bounce transpose -> coalesced 16B packed stores (overlays Sh).
__global__ __launch_bounds__(256) void gemm_qkv(
    const ushort* __restrict__ A,   // [32768][256] bf16
    const ushort* __restrict__ Bw,  // [768][256] bf16
    const float* __restrict__ bq,
    ushort* __restrict__ Q, ushort* __restrict__ K, ushort* __restrict__ Vf) {
    __shared__ short Sh[32768];     // 64KB: As0@0 As1@8192 Bs0@16384 Bs1@24576
                                    // epilogue: 128x136 bf16 tile @0 (post-barrier)
    const int t = threadIdx.x;
    const int wv = t >> 6, lane = t & 63, quad = lane >> 4, col = lane & 15;
    const int m0 = blockIdx.y * 128, n0 = blockIdx.x * 128;
    const int wm = (wv & 1) * 64, wn = (wv >> 1) * 64;

    floatx4 zf = {0.f, 0.f, 0.f, 0.f};
    floatx4 acc[4][4];
#pragma unroll
    for (int i = 0; i < 4; ++i)
#pragma unroll
        for (int j = 0; j < 4; ++j) acc[i][j] = zf;

    // per-thread staging address pieces (same swizzle as before)
    const int srow = t >> 3, sqs = t & 7;
    const int sqg = sqs ^ (srow & 7);

    // ---- prologue: stage K-tile 0 into buffer 0 ----
#pragma unroll
    for (int i = 0; i < 4; ++i) {
        int row = (i * 256 + t) >> 3;
        int qg = ((i * 256 + t) & 7) ^ (row & 7);
        gl_lds16(A + (size_t)(m0 + row) * 256 + 0 + qg * 8,
                 Sh + (i * 256 + wv * 64) * 8);
        gl_lds16(Bw + (size_t)(n0 + row) * 256 + 0 + qg * 8,
                 Sh + 16384 + (i * 256 + wv * 64) * 8);
    }
    __syncthreads();

    int cur = 0;
    for (int kt = 0; kt < 4; ++kt) {
        int nxt = cur ^ 1;
        if (kt < 3) {
            int kk = (kt + 1) * 64;
#pragma unroll
            for (int i = 0; i < 4; ++i) {
                int row = (i * 256 + t) >> 3;
                int qg = ((i * 256 + t) & 7) ^ (row & 7);
                gl_lds16(A + (size_t)(m0 + row) * 256 + kk + qg * 8,
                         Sh + nxt * 8192 + (i * 256 + wv * 64) * 8);
                gl_lds16(Bw + (size_t)(n0 + row) * 256 + kk + qg * 8,
                         Sh + 16384 + nxt * 8192 + (i * 256 + wv * 64) * 8);
            }
        }
        const short* As = Sh + cur * 8192;
        const short* Bs = Sh + 16384 + cur * 8192;
#pragma unroll
        for (int h = 0; h < 2; ++h) {
            short8 af[4], bf[4];
#pragma unroll
            for (int mi = 0; mi < 4; ++mi) {
                int row = wm + mi * 16 + col;
                af[mi] = *(const short8*)(As + (row * 8 + ((h * 4 + quad) ^ (row & 7))) * 8);
            }
#pragma unroll
            for (int ni = 0; ni < 4; ++ni) {
                int row = wn + ni * 16 + col;
                bf[ni] = *(const short8*)(Bs + (row * 8 + ((h * 4 + quad) ^ (row & 7))) * 8);
            }
#pragma unroll
            for (int mi = 0; mi < 4; ++mi)
#pragma unroll
                for (int ni = 0; ni < 4; ++ni)
                    acc[mi][ni] = __builtin_amdgcn_mfma_f32_16x16x32_bf16(af[mi], bf[ni], acc[mi][ni], 0, 0, 0);
        }
        __syncthreads();   // compute-buffer reads done AND next-tile loads landed
        cur = nxt;
    }
    (void)srow; (void)sqg;

    const int bx = blockIdx.x;   // 0,1: Q   2,3: K   4,5: V  (block-uniform)
    if (bx >= 4) {
        // ---- V: direct packed stores (fragment order already n-contiguous) ----
#pragma unroll
        for (int ni = 0; ni < 4; ++ni) {
            int j = n0 + wn + ni * 16 + col;
            int head = (j >> 5) & 7, hd = j & 31;
            float bias = bq[j];
            int h = hd >> 4, colv = hd & 15;
#pragma unroll
            for (int mi = 0; mi < 4; ++mi) {
                int mb = m0 + wm + mi * 16 + quad * 4;   // n&3 = r, contiguous
                int w = mb >> 9, n = mb & 511;
                size_t off = ((size_t)((w * 8 + head) * 64 + (n >> 4) * 2 + h) << 8)
                           + ((((n >> 2) & 3) * 16 + colv) << 2);
                uint2v pv;
                pv[0] = pk2bf(acc[mi][ni][0] + bias, acc[mi][ni][1] + bias);
                pv[1] = pk2bf(acc[mi][ni][2] + bias, acc[mi][ni][3] + bias);
                *(uint2v*)(Vf + off) = pv;
            }
        }
    } else {
        // ---- Q/K: LDS-bounce -> 8 coalesced 16B stores/thread (Sh reused) ----
        __syncthreads();   // all waves past main loop; Sh free
#pragma unroll
        for (int ni = 0; ni < 4; ++ni) {
            int j = n0 + wn + ni * 16 + col;
            int jloc = wn + ni * 16 + col;
            float bias = bq[j] * ((j < 256) ? (QSCALE * LOG2E) : 1.0f);
#pragma unroll
            for (int mi = 0; mi < 4; ++mi) {
                int rowb = wm + mi * 16 + quad * 4;
#pragma unroll
                for (int r = 0; r < 4; ++r)
                    Sh[(rowb + r) * 136 + jloc] = (short)f2bf(acc[mi][ni][r] + bias);
            }
        }
        __syncthreads();
        ushort* dst = (bx < 2) ? Q : K;
#pragma unroll
        for (int k8 = 0; k8 < 8; ++k8) {
            int chunk = k8 * 256 + t;        // 0..2047
            int row = chunk >> 4;            // 0..127
            int jl = (chunk & 15) * 8;       // 0..120
            int j = n0 + jl;
            int m = m0 + row;
            int w = m >> 9, n = m & 511;
            int head = (j >> 5) & 7;
            uint4v vv = *(const uint4v*)(Sh + row * 136 + jl);
            size_t off;
            if (bx < 2) {
                int hd = j & 31;
                off = ((size_t)(w * 8 + head) * 512 + n) * 32 + hd;          // row-major
            } else {
                int hd = j & 31;
                off = ((size_t)(w * 8 + head) << 14) + ((size_t)(n >> 4) << 9)
                    + (((hd >> 3) * 16 + (n & 15)) << 3);                    // frag order
            }
            *(uint4v*)(dst + off) = vv;
        }
    }
}

// ---------------- MFMA GEMM: out = Y @ Wpb^T + bp, scatter w/ reverse shift ----------
// 2-phase double-buffered staging; epilogue LDS-bounce overlays the same 64KB.
__global__ __launch_bounds__(256) void gemm_proj(
    const ushort* __restrict__ A,   // Y [32768][256] bf16
    const ushort* __restrict__ Bw,  // [256][256] bf16
    const float* __restrict__ bp,
    float* __restrict__ out) {
    __shared__ short Sh[32768];     // 64KB: As0@0 As1@8192 Bs0@16384 Bs1@24576
    float* Shf = (float*)Sh;        // epilogue: 64x132 f32 bounce (33.8KB, post-barrier)
    const int t = threadIdx.x;
    const int wv = t >> 6, lane = t & 63, quad = lane >> 4, col = lane & 15;
    const int m0 = blockIdx.y * 128, n0 = blockIdx.x * 128;
    const int wm = (wv & 1) * 64, wn = (wv >> 1) * 64;

    floatx4 zf = {0.f, 0.f, 0.f, 0.f};
    floatx4 acc[4][4];
#pragma unroll
    for (int i = 0; i < 4; ++i)
#pragma unroll
        for (int j = 0; j < 4; ++j) acc[i][j] = zf;

    // ---- prologue: stage K-tile 0 into buffer 0 ----
#pragma unroll
    for (int i = 0; i < 4; ++i) {
        int row = (i * 256 + t) >> 3;
        int qg = ((i * 256 + t) & 7) ^ (row & 7);
        gl_lds16(A + (size_t)(m0 + row) * 256 + 0 + qg * 8,
                 Sh + (i * 256 + wv * 64) * 8);
        gl_lds16(Bw + (size_t)(n0 + row) * 256 + 0 + qg * 8,
                 Sh + 16384 + (i * 256 + wv * 64) * 8);
    }
    __syncthreads();

    int cur = 0;
    for (int kt = 0; kt < 4; ++kt) {
        int nxt = cur ^ 1;
        if (kt < 3) {
            int kk = (kt + 1) * 64;
#pragma unroll
            for (int i = 0; i < 4; ++i) {
                int row = (i * 256 + t) >> 3;
                int qg = ((i * 256 + t) & 7) ^ (row & 7);
                gl_lds16(A + (size_t)(m0 + row) * 256 + kk + qg * 8,
                         Sh + nxt * 8192 + (i * 256 + wv * 64) * 8);
                gl_lds16(Bw + (size_t)(n0 + row) * 256 + kk + qg * 8,
                         Sh + 16384 + nxt * 8192 + (i * 256 + wv * 64) * 8);
            }
        }
        const short* As = Sh + cur * 8192;
        const short* Bs = Sh + 16384 + cur * 8192;
#pragma unroll
        for (int h = 0; h < 2; ++h) {
            short8 af[4], bf[4];
#pragma unroll
            for (int mi = 0; mi < 4; ++mi) {
                int row = wm + mi * 16 + col;
                af[mi] = *(const short8*)(As + (row * 8 + ((h * 4 + quad) ^ (row & 7))) * 8);
            }
#pragma unroll
            for (int ni = 0; ni < 4; ++ni) {
                int row = wn + ni * 16 + col;
                bf[ni] = *(const short8*)(Bs + (row * 8 + ((h * 4 + quad) ^ (row & 7))) * 8);
            }
#pragma unroll
            for (int mi = 0; mi < 4; ++mi)
#pragma unroll
                for (int ni = 0; ni < 4; ++ni)
                    acc[mi][ni] = __builtin_amdgcn_mfma_f32_16x16x32_bf16(af[mi], bf[ni], acc[mi][ni], 0, 0, 0);
        }
        __syncthreads();
        cur = nxt;
    }

    // ---- epilogue: bounce 2 half-tiles (64 rows x 128 f32) through Shf ----
    float biasv[4];
#pragma unroll
    for (int ni = 0; ni < 4; ++ni) biasv[ni] = bp[n0 + wn + ni * 16 + col];

#pragma unroll
    for (int h2 = 0; h2 < 2; ++h2) {
        __syncthreads();                    // Shf free (main-loop / prev-half reads done)
        if ((wv & 1) == h2) {               // waves owning rows [h2*64, h2*64+64)
#pragma unroll
            for (int ni = 0; ni < 4; ++ni) {
                int jloc = wn + ni * 16 + col;
#pragma unroll
                for (int mi = 0; mi < 4; ++mi) {
                    int rl = mi * 16 + quad * 4;     // local row 0..63
#pragma unroll
                    for (int r = 0; r < 4; ++r)
                        Shf[(rl + r) * 132 + jloc] = acc[mi][ni][r] + biasv[ni];
                }
            }
        }
        __syncthreads();
        // 4 threads per row; each stores 8 float4 (64B contiguous per 4-lane group)
        int row = t >> 2;                   // 0..63
        int m = m0 + h2 * 64 + row;
        float* ob = out + spatial_off(m) + n0 + (t & 3) * 4;
        const float* sb = Shf + row * 132 + (t & 3) * 4;
#pragma unroll
        for (int k = 0; k < 8; ++k)
            *(float4*)(ob + k * 16) = *(const float4*)(sb + k * 16);
    }
}

// ---------------- MFMA windowed attention (v8, best measured: 47.5us) ----------------
// 512 threads (8 waves), grid 512, one-shot K/V staging (77.5KB LDS, 2 blocks/CU),
// K/V pre-permuted to fragment order in global, raw v_exp_f32, (512,2) bounds.
// Converged: chunked/grid-split occupancy (r8-r9) and q-pairing (r12-r13) were
// nulls; kernel sits at a VALU+latency equilibrium ~48us.
__global__ __launch_bounds__(512, 2) void attn_kernel(
    const ushort* __restrict__ Q, const ushort* __restrict__ K,
    const ushort* __restrict__ Vf, const uint* __restrict__ Up,
    ushort* __restrict__ Y) {
    __shared__ short Kl[512 * 32];       // QK A-fragment order (pre-permuted in global)
    __shared__ short Vs[64 * 256];       // PV A-fragment order (pre-permuted in global)
    __shared__ uint  Ul[3375];           // per-head rel-pos pair table (log2-scaled)

    const int t = threadIdx.x;
    const int bid = blockIdx.x;
    const int w = bid >> 3, head = bid & 7;
    const int wh = w >> 4, ww = (w >> 2) & 3, wd = w & 3;
    const int wv = t >> 6, lane = t & 63, quad = lane >> 4, col = lane & 15;

    const ushort* Kg = K + (size_t)(w * 8 + head) * 512 * 32;
    const ushort* Vg = Vf + (size_t)(w * 8 + head) * 512 * 32;
    const ushort* Qg = Q + (size_t)(w * 8 + head) * 512 * 32;

    // ---- stage K and V once (async direct-to-LDS, linear; 512 threads x 4 iters) ----
#pragma unroll
    for (int i = 0; i < 4; ++i) {
        gl_lds16(Kg + (size_t)(i * 512 + t) * 8, Kl + (i * 512 + wv * 64) * 8);
        gl_lds16(Vg + (size_t)(i * 512 + t) * 8, Vs + (i * 512 + wv * 64) * 8);
    }
    // ---- stage this head's pair table ----
    const uint* Uph = Up + head * 3375;
    for (int i = t; i < 3375; i += 512) Ul[i] = Uph[i];
    __syncthreads();

    const bool boundary = (wh == 3) | (ww == 3) | (wd == 3);
    floatx4 zf = {0.f, 0.f, 0.f, 0.f};

    for (int qs = 0; qs < 4; ++qs) {
        const int qt = wv * 4 + qs;
        const short8 qf = *(const short8*)(Qg + (size_t)(qt * 16 + col) * 32 + quad * 8);

        const int qrow = qt * 16 + col;
        const int qh = qrow >> 6, qw = (qrow >> 3) & 7, qd = qrow & 7;
        const int Base0 = ((qh + 7) * 15 + (qw + 7 - (quad >> 1))) * 15
                        + (qd - ((quad & 1) << 2) + 7);
        const int cq = ((wh == 3) ? (1 + ((qrow >> 8) & 1)) * 16 : 0)
                     + ((ww == 3) ? (1 + ((qrow >> 5) & 1)) * 4 : 0)
                     + ((wd == 3) ? (1 + ((qrow >> 2) & 1)) : 0);

        float rs = 0.f;
        floatx4 o0 = zf, o1 = zf;

        // ---- keys in 2 chunks of 256: acc[16] produced & consumed per chunk ----
        for (int c = 0; c < 2; ++c) {   // rolled: keeps register liveness low
            const short* KlC = Kl + c * 8192;
            const short* VsC = Vs + c * 8192;
            const int BaseC = Base0 - c * 900;
            const int ckh = (wh == 3) ? ((1 + c) * 16) : 0;

            floatx4 acc[16];
            // produce: S^T tiles with bias (and mask) preloaded into the C operand
#pragma unroll
            for (int tt = 0; tt < 16; ++tt) {
                const int Kt2 = ((tt >> 2) * 15 + (tt & 3) * 2) * 15;
                uint p0 = Ul[BaseC - Kt2];
                uint p1 = Ul[BaseC - Kt2 - 2];
                floatx4 cf;
                cf[0] = __uint_as_float(p0 << 16);
                cf[1] = __uint_as_float(p0 & 0xffff0000u);
                cf[2] = __uint_as_float(p1 << 16);
                cf[3] = __uint_as_float(p1 & 0xffff0000u);
                if (boundary) {
                    int ck = ckh
                           + ((ww == 3) ? (1 + ((tt >> 1) & 1)) * 4 : 0)
                           + ((wd == 3) ? (1 + (quad & 1)) : 0);
                    float madd = (cq == ck) ? 0.f : -144.269504f;  // -100*log2e
                    cf[0] += madd; cf[1] += madd; cf[2] += madd; cf[3] += madd;
                }
                short8 kf = *(const short8*)(KlC + tt * 512 + lane * 8);
                acc[tt] = __builtin_amdgcn_mfma_f32_16x16x32_bf16(kf, qf, cf, 0, 0, 0);
            }

            // consume: raw v_exp (scores already in log2 domain), pack, PV
#pragma unroll
            for (int tt = 0; tt < 16; ++tt) {
                float e0 = __builtin_amdgcn_exp2f(acc[tt][0]);
                float e1 = __builtin_amdgcn_exp2f(acc[tt][1]);
                float e2 = __builtin_amdgcn_exp2f(acc[tt][2]);
                float e3 = __builtin_amdgcn_exp2f(acc[tt][3]);
                rs += (e0 + e1) + (e2 + e3);
                uint2v pp;
                pp[0] = pk2bf(e0, e1);
                pp[1] = pk2bf(e2, e3);
                s4v pf = __builtin_bit_cast(s4v, pp);
                s4v v0 = *(const s4v*)(VsC + ((tt * 2 + 0) << 8) + lane * 4);
                s4v v1 = *(const s4v*)(VsC + ((tt * 2 + 1) << 8) + lane * 4);
                o0 = __builtin_amdgcn_mfma_f32_16x16x16bf16_1k(v0, pf, o0, 0, 0, 0);
                o1 = __builtin_amdgcn_mfma_f32_16x16x16bf16_1k(v1, pf, o1, 0, 0, 0);
            }
        }

        rs += __shfl_xor(rs, 16);
        rs += __shfl_xor(rs, 32);
        const float inv = __builtin_amdgcn_rcpf(rs);

        // ---- epilogue: O^T row=hd(quad*4+r), col=q(lane&15); two packed 8B stores ----
        int token = w * 512 + qt * 16 + col;
        ushort* Yb = Y + (size_t)token * 256 + head * 32 + quad * 4;
        uint2v y0, y1;
        y0[0] = pk2bf(o0[0] * inv, o0[1] * inv);
        y0[1] = pk2bf(o0[2] * inv, o0[3] * inv);
        y1[0] = pk2bf(o1[0] * inv, o1[1] * inv);
        y1[1] = pk2bf(o1[2] * inv, o1[3] * inv);
        *(uint2v*)(Yb) = y0;
        *(uint2v*)(Yb + 16) = y1;
    }
}

extern "C" void kernel_launch(void* const* d_in, const int* in_sizes, int n_in,
                              void* d_out, int out_size, void* d_ws, size_t ws_size,
                              hipStream_t stream) {
    const float* x      = (const float*)d_in[0];
    const float* qkv_w  = (const float*)d_in[1];
    const float* qkv_b  = (const float*)d_in[2];
    const float* proj_w = (const float*)d_in[3];
    const float* proj_b = (const float*)d_in[4];
    const float* rpb    = (const float*)d_in[5];
    float* out = (float*)d_out;

    // ws layout (ushorts): Xw 8.39M | Q 8.39M | K 8.39M | Vf 8.39M | Y 8.39M | Up 54K | Wqb | Wpb
    ushort* Xw  = (ushort*)d_ws;
    ushort* Q   = Xw + 8388608;
    ushort* K   = Q + 8388608;
    ushort* Vf  = K + 8388608;
    ushort* Y   = Vf + 8388608;
    uint*   Up  = (uint*)(Y + 8388608);
    ushort* Wqb = (ushort*)(Up + 27008);
    ushort* Wpb = Wqb + 196608;

    prep<<<dim3(5226), dim3(256), 0, stream>>>(x, qkv_w, proj_w, rpb, Xw, Wqb, Wpb, Up);
    gemm_qkv<<<dim3(6, 256), dim3(256), 0, stream>>>(Xw, Wqb, qkv_b, Q, K, Vf);
    attn_kernel<<<dim3(512), dim3(512), 0, stream>>>(Q, K, Vf, Up, Y);
    gemm_proj<<<dim3(2, 256), dim3(256), 0, stream>>>(Y, Wpb, proj_b, out);
}